// Round 4
// baseline (460.146 us; speedup 1.0000x reference)
//
#include <hip/hip_runtime.h>

// Problem constants (from reference setup_inputs)
#define B 4
#define C 3
#define H 1024
#define W 1024
#define N (H * W)
#define EPS 1e-8f

// Ownership-gather tiling: each block OWNS a TWxTH output tile (exclusive),
// gathers all source pixels in the tile + R halo window. Corners inside the
// tile -> LDS atomic; flush = plain coalesced float4 stores (no global
// atomics). (source,corner) pairs not covered by the corner-owner's window
// (exact check) are appended as outlier records, applied by a tiny kernel.
#define TW 64
#define TH 32
#define R 8
#define WINW (TW + 2 * R)      // 80
#define WINH (TH + 2 * R)      // 48
#define NGRP (WINW / 4)        // 20 float4-groups per window row
#define NTASK (NGRP * WINH)    // 960 tasks per block
#define TCELLS (TW * TH)       // 2048 owned cells -> 4 planes * 8KB = 32KB LDS
#define NTX (W / TW)           // 16
#define NTY (H / TH)           // 32

struct OutlierRec { int idx; float dw, d0, d1, d2; };  // idx = b*N + cell

__global__ __launch_bounds__(512) void splat_gather(
    const float* __restrict__ im0,   // [B,C,H,W]
    const float* __restrict__ grid,  // [B,H,W,2]
    float* __restrict__ out,         // [B,C,H,W] numerators (fully overwritten)
    float* __restrict__ den,         // [B,N] denominators (fully overwritten)
    int* __restrict__ counter,       // outlier count (pre-zeroed)
    OutlierRec* __restrict__ recs,   // outlier records
    int cap)
{
    __shared__ float sden[TCELLS];
    __shared__ float sc0[TCELLS];
    __shared__ float sc1[TCELLS];
    __shared__ float sc2[TCELLS];

    const int bid = blockIdx.x;
    const int b = bid >> 9;            // NTX*NTY = 512 tiles per image
    const int t = bid & 511;
    const int tx0 = (t & (NTX - 1)) * TW;
    const int ty0 = (t >> 4) * TH;
    const int tid = threadIdx.x;

    {
        float4 z = make_float4(0.f, 0.f, 0.f, 0.f);
        ((float4*)sden)[tid] = z;
        ((float4*)sc0)[tid] = z;
        ((float4*)sc1)[tid] = z;
        ((float4*)sc2)[tid] = z;
    }
    __syncthreads();

    const int lx0 = tx0 - R;
    const int ly0 = ty0 - R;

    const float* imb   = im0 + (size_t)b * C * N;
    const float* gbase = grid + (size_t)b * N * 2;

    // --- Prologue: issue ALL loads for both tasks (software pipeline) ---
    // Task A: window group tid; Task B: window group tid+512.
    // Groups of 4 pixels are 16B-aligned and never straddle image edges
    // (tile origins and W are multiples of 4).
    float4 gA0, gA1, vA0, vA1, vA2; int sxA = 0, syA = 0; bool okA = false;
    float4 gB0, gB1, vB0, vB1, vB2; int sxB = 0, syB = 0; bool okB = false;

    {
        const int task = tid;              // < 960 always
        const int row = task / NGRP;
        const int grp = task - row * NGRP;
        syA = ly0 + row;
        sxA = lx0 + grp * 4;
        if ((unsigned)syA < H && (unsigned)sxA < W) {
            okA = true;
            const int n = syA * W + sxA;
            gA0 = *(const float4*)(gbase + 2 * n);
            gA1 = *(const float4*)(gbase + 2 * n + 4);
            vA0 = *(const float4*)(imb + n);
            vA1 = *(const float4*)(imb + N + n);
            vA2 = *(const float4*)(imb + 2 * N + n);
        }
    }
    {
        const int task = tid + 512;
        if (task < NTASK) {
            const int row = task / NGRP;
            const int grp = task - row * NGRP;
            syB = ly0 + row;
            sxB = lx0 + grp * 4;
            if ((unsigned)syB < H && (unsigned)sxB < W) {
                okB = true;
                const int n = syB * W + sxB;
                gB0 = *(const float4*)(gbase + 2 * n);
                gB1 = *(const float4*)(gbase + 2 * n + 4);
                vB0 = *(const float4*)(imb + n);
                vB1 = *(const float4*)(imb + N + n);
                vB2 = *(const float4*)(imb + 2 * N + n);
            }
        }
    }

    auto do_pixel = [&](float gx, float gy, float v0, float v1, float v2,
                        int sx, int sy) {
        const float x0f = floorf(gx);
        const float y0f = floorf(gy);
        const float dx = gx - x0f;
        const float dy = gy - y0f;
        const int x0 = (int)x0f;
        const int y0 = (int)y0f;
        const float wxa[2] = {1.f - dx, dx};
        const float wya[2] = {1.f - dy, dy};
        const bool src_owner =
            ((unsigned)(sx - tx0) < TW) && ((unsigned)(sy - ty0) < TH);
#pragma unroll
        for (int cy = 0; cy < 2; ++cy) {
#pragma unroll
            for (int cx = 0; cx < 2; ++cx) {
                const int xi = x0 + cx;
                const int yi = y0 + cy;
                const int clx = xi - tx0;
                const int cly = yi - ty0;
                const float wgt = wxa[cx] * wya[cy];
                if ((unsigned)clx < TW && (unsigned)cly < TH) {
                    const int li = cly * TW + clx;
                    unsafeAtomicAdd(&sden[li], wgt);
                    unsafeAtomicAdd(&sc0[li], v0 * wgt);
                    unsafeAtomicAdd(&sc1[li], v1 * wgt);
                    unsafeAtomicAdd(&sc2[li], v2 * wgt);
                } else if (src_owner && (unsigned)xi < W && (unsigned)yi < H) {
                    // exact: does the corner-owner's window cover this source?
                    const int ox0 = (xi >> 6) * TW;
                    const int oy0 = (yi >> 5) * TH;
                    const bool covered =
                        (sx >= ox0 - R) && (sx < ox0 + TW + R) &&
                        (sy >= oy0 - R) && (sy < oy0 + TH + R);
                    if (!covered) {
                        const int slot = atomicAdd(counter, 1);
                        if (slot < cap) {
                            OutlierRec r;
                            r.idx = b * N + yi * W + xi;
                            r.dw = wgt;
                            r.d0 = v0 * wgt; r.d1 = v1 * wgt; r.d2 = v2 * wgt;
                            recs[slot] = r;
                        }
                    }
                }
            }
        }
    };

    if (okA) {
        do_pixel(gA0.x, gA0.y, vA0.x, vA1.x, vA2.x, sxA + 0, syA);
        do_pixel(gA0.z, gA0.w, vA0.y, vA1.y, vA2.y, sxA + 1, syA);
        do_pixel(gA1.x, gA1.y, vA0.z, vA1.z, vA2.z, sxA + 2, syA);
        do_pixel(gA1.z, gA1.w, vA0.w, vA1.w, vA2.w, sxA + 3, syA);
    }
    if (okB) {
        do_pixel(gB0.x, gB0.y, vB0.x, vB1.x, vB2.x, sxB + 0, syB);
        do_pixel(gB0.z, gB0.w, vB0.y, vB1.y, vB2.y, sxB + 1, syB);
        do_pixel(gB1.x, gB1.y, vB0.z, vB1.z, vB2.z, sxB + 2, syB);
        do_pixel(gB1.z, gB1.w, vB0.w, vB1.w, vB2.w, sxB + 3, syB);
    }
    __syncthreads();

    // Flush owned tile with plain coalesced float4 stores (exclusive ownership).
    {
        const int cell = tid * 4;               // 512 threads * 4 cells = 2048
        const int cly = cell >> 6;              // /TW
        const int clx = cell & (TW - 1);
        const int gi = (ty0 + cly) * W + tx0 + clx;
        float* outb = out + (size_t)b * C * N;
        ((float4*)(den + (size_t)b * N + gi))[0] = ((const float4*)sden)[tid];
        ((float4*)(outb + gi))[0]           = ((const float4*)sc0)[tid];
        ((float4*)(outb + N + gi))[0]       = ((const float4*)sc1)[tid];
        ((float4*)(outb + 2 * N + gi))[0]   = ((const float4*)sc2)[tid];
    }
}

__global__ __launch_bounds__(256) void apply_outliers(
    float* __restrict__ out,         // [B,C,N]
    float* __restrict__ den,         // [B,N]
    const int* __restrict__ counter,
    const OutlierRec* __restrict__ recs,
    int cap)
{
    const int count = min(*counter, cap);
    for (int i = blockIdx.x * blockDim.x + threadIdx.x; i < count;
         i += gridDim.x * blockDim.x) {
        OutlierRec r = recs[i];
        const int b = r.idx >> 20;          // idx / N
        const int cell = r.idx & (N - 1);
        float* outb = out + (size_t)b * C * N + cell;
        unsafeAtomicAdd(&den[r.idx], r.dw);
        unsafeAtomicAdd(outb, r.d0);
        unsafeAtomicAdd(outb + N, r.d1);
        unsafeAtomicAdd(outb + 2 * N, r.d2);
    }
}

// Normalize: load den once per spatial quad, apply reciprocal to 3 channels.
__global__ __launch_bounds__(256) void normalize_kernel(
    float* __restrict__ out,        // [B,C,N]
    const float* __restrict__ den)  // [B,N]
{
    const int t = blockIdx.x * blockDim.x + threadIdx.x;  // over B*(N/4)
    if (t >= B * (N / 4)) return;
    const int b = t >> 18;                 // t / (N/4), N/4 = 2^18
    const int i = (t & ((N / 4) - 1)) * 4;

    const float4 d = *(const float4*)(den + (size_t)b * N + i);
    float4 r;
    r.x = 1.f / fmaxf(d.x, EPS);
    r.y = 1.f / fmaxf(d.y, EPS);
    r.z = 1.f / fmaxf(d.z, EPS);
    r.w = 1.f / fmaxf(d.w, EPS);

    float* outb = out + (size_t)b * C * N + i;
#pragma unroll
    for (int c = 0; c < C; ++c) {
        float4 v = *(float4*)(outb + (size_t)c * N);
        v.x *= r.x; v.y *= r.y; v.z *= r.z; v.w *= r.w;
        *(float4*)(outb + (size_t)c * N) = v;
    }
}

extern "C" void kernel_launch(void* const* d_in, const int* in_sizes, int n_in,
                              void* d_out, int out_size, void* d_ws, size_t ws_size,
                              hipStream_t stream) {
    const float* im0 = (const float*)d_in[0];   // [B,C,H,W] fp32
    const float* grid = (const float*)d_in[1];  // [B,H,W,2] fp32
    float* out = (float*)d_out;                 // [B,C,H,W] fp32

    // d_ws layout: [0,4): outlier counter | [1024, 1024+16MB): den | records
    int* counter = (int*)d_ws;
    float* den = (float*)((char*)d_ws + 1024);
    const size_t rec_off = 1024 + (size_t)B * N * sizeof(float);
    OutlierRec* recs = (OutlierRec*)((char*)d_ws + rec_off);
    long long cap_ll = 0;
    if (ws_size > rec_off) cap_ll = (long long)((ws_size - rec_off) / sizeof(OutlierRec));
    int cap = (int)(cap_ll > (1 << 20) ? (1 << 20) : cap_ll);

    hipMemsetAsync(counter, 0, sizeof(int), stream);  // only the counter

    {
        int blocks = NTX * NTY * B;  // 2048
        splat_gather<<<blocks, 512, 0, stream>>>(im0, grid, out, den, counter, recs, cap);
    }
    apply_outliers<<<128, 256, 0, stream>>>(out, den, counter, recs, cap);
    {
        int total = B * (N / 4);
        normalize_kernel<<<(total + 255) / 256, 256, 0, stream>>>(out, den);
    }
}

// Round 7
// 215.538 us; speedup vs baseline: 2.1349x; 2.1349x over previous
//
#include <hip/hip_runtime.h>
#include <hip/hip_fp16.h>

// Problem constants (from reference setup_inputs)
#define B 4
#define C 3
#define H 1024
#define W 1024
#define N (H * W)
#define EPS 1e-8f

// Bin-and-gather splat: each block owns a 32x32 output tile. Sources from the
// tile+8px window are binned in LDS by their integer cell (x0,y0) (one u32 LDS
// atomic per source). Each output cell then GATHERS from its 4 neighboring
// bins, accumulating den + 3 channels in fp32 REGISTERS -- no fp atomics
// anywhere. dx,dy kept fp32 (weight precision); v stored fp16 (error enters as
// weighted average -> bounded ~3e-3 regardless of den). Bin overflow and
// window outliers go through exact fp32 per-tile records + fix_tiles.
#define TW 32
#define TH 32
#define R 8
#define WIN 48                 // TW + 2R
#define NSRC (WIN * WIN)       // 2304 window sources
#define NTASKS (NSRC / 4)      // 576 float4-groups
#define BDIM 33                // bins per axis: x0 in [tx0-1, tx0+31]
#define NBINS (BDIM * BDIM)    // 1089
#define K 6                    // bin capacity (Poisson(1): P(>6) ~ 8e-5)
#define NTX (W / TW)           // 32
#define NTY (H / TH)           // 32
#define NTILES (NTX * NTY * B) // 4096

struct OutlierRec { int idx; float dw, d0, d1, d2; };  // idx = b*N + cell

__global__ __launch_bounds__(256) void splat_gather(
    const float* __restrict__ im0,   // [B,C,H,W]
    const float* __restrict__ grid,  // [B,H,W,2]
    float* __restrict__ out,         // [B,C,H,W] NORMALIZED output
    float* __restrict__ den,         // [B,N] denominators (for fixup)
    int* __restrict__ tileCnt,       // [NTILES] record counts (pre-zeroed)
    OutlierRec* __restrict__ recs,   // [NTILES*slots]
    int slots)
{
    __shared__ float    recDx[NSRC];
    __shared__ float    recDy[NSRC];
    __shared__ unsigned recV01[NSRC];    // half2(v0,v1) bits
    __shared__ unsigned recV2[NSRC];     // half(v2) bits
    __shared__ unsigned binCnt[NBINS];
    __shared__ unsigned short ent[NBINS * K];

    const int bid = blockIdx.x;
    const int b = bid >> 10;             // 1024 tiles per image
    const int t = bid & 1023;
    const int tx0 = (t & (NTX - 1)) * TW;
    const int ty0 = (t >> 5) * TH;
    const int tid = threadIdx.x;

    for (int i = tid; i < NBINS; i += 256) binCnt[i] = 0u;
    __syncthreads();

    const int lx0 = tx0 - R;
    const int ly0 = ty0 - R;

    const float* imb   = im0 + (size_t)b * C * N;
    const float* gbase = grid + (size_t)b * N * 2;

    // helper: push an exact fp32 record to a tile's fixup list
    auto push_rec = [&](int xi, int yi, float w, float v0, float v1, float v2) {
        const int tile = (b << 10) | ((yi >> 5) << 5) | (xi >> 5);
        const int slot = atomicAdd(&tileCnt[tile], 1);
        if (slot < slots) {
            OutlierRec r;
            r.idx = b * N + yi * W + xi;
            r.dw = w; r.d0 = v0 * w; r.d1 = v1 * w; r.d2 = v2 * w;
            recs[(size_t)tile * slots + slot] = r;
        }
    };

    // ---- Phase A: load window, write records, bin by (x0,y0) ----
    for (int task = tid; task < NTASKS; task += 256) {
        const int row = task / (WIN / 4);              // 0..47
        const int col = (task - row * (WIN / 4)) * 4;  // 0,4,...,44
        const int sy = ly0 + row;
        const int sxg = lx0 + col;
        // groups are 16B aligned and never straddle edges (tx0,R mult of 4)
        if ((unsigned)sy >= H || (unsigned)sxg >= W) continue;

        const int n = sy * W + sxg;
        const float4 g0 = *(const float4*)(gbase + 2 * n);
        const float4 g1 = *(const float4*)(gbase + 2 * n + 4);
        const float4 c0 = *(const float4*)(imb + n);
        const float4 c1 = *(const float4*)(imb + N + n);
        const float4 c2 = *(const float4*)(imb + 2 * N + n);

        const float gxk[4] = {g0.x, g0.z, g1.x, g1.z};
        const float gyk[4] = {g0.y, g0.w, g1.y, g1.w};
        const float v0k[4] = {c0.x, c0.y, c0.z, c0.w};
        const float v1k[4] = {c1.x, c1.y, c1.z, c1.w};
        const float v2k[4] = {c2.x, c2.y, c2.z, c2.w};

#pragma unroll
        for (int k = 0; k < 4; ++k) {
            const int sx = sxg + k;
            const int i = task * 4 + k;          // window record index
            const float gx = gxk[k], gy = gyk[k];
            const float x0f = floorf(gx);
            const float y0f = floorf(gy);
            const float dx = gx - x0f;
            const float dy = gy - y0f;
            const int x0 = (int)x0f;
            const int y0 = (int)y0f;

            recDx[i] = dx;
            recDy[i] = dy;
            {
                __half2 h01 = __floats2half2_rn(v0k[k], v1k[k]);
                recV01[i] = *(unsigned*)&h01;
                __half2 h2 = __floats2half2_rn(v2k[k], 0.f);
                recV2[i] = *(unsigned*)&h2;
            }

            const int bx = x0 - tx0 + 1;         // shifted bin coords
            const int by = y0 - ty0 + 1;
            if ((unsigned)bx < BDIM && (unsigned)by < BDIM) {
                const int bin = by * BDIM + bx;
                const unsigned slot = atomicAdd(&binCnt[bin], 1u);
                if (slot < K) {
                    ent[bin * K + slot] = (unsigned short)i;
                } else {
                    // overflow: push exact records for corners in MY tile
                    const float wxa[2] = {1.f - dx, dx};
                    const float wya[2] = {1.f - dy, dy};
#pragma unroll
                    for (int cy = 0; cy < 2; ++cy)
#pragma unroll
                        for (int cx = 0; cx < 2; ++cx) {
                            const int xi = x0 + cx, yi = y0 + cy;
                            if ((unsigned)(xi - tx0) < TW &&
                                (unsigned)(yi - ty0) < TH)
                                push_rec(xi, yi, wxa[cx] * wya[cy],
                                         v0k[k], v1k[k], v2k[k]);
                        }
                }
            }

            // owner-outlier check: corners whose owner-tile window misses us
            if ((unsigned)(sx - tx0) < TW && (unsigned)(sy - ty0) < TH) {
                const float wxa[2] = {1.f - dx, dx};
                const float wya[2] = {1.f - dy, dy};
#pragma unroll
                for (int cy = 0; cy < 2; ++cy)
#pragma unroll
                    for (int cx = 0; cx < 2; ++cx) {
                        const int xi = x0 + cx, yi = y0 + cy;
                        if ((unsigned)xi < W && (unsigned)yi < H) {
                            const int ox0 = (xi >> 5) << 5;
                            const int oy0 = (yi >> 5) << 5;
                            const bool covered =
                                (sx >= ox0 - R) && (sx < ox0 + TW + R) &&
                                (sy >= oy0 - R) && (sy < oy0 + TH + R);
                            if (!covered)
                                push_rec(xi, yi, wxa[cx] * wya[cy],
                                         v0k[k], v1k[k], v2k[k]);
                        }
                    }
            }
        }
    }
    __syncthreads();

    // ---- Phase B: gather per output cell, fp32 register accumulation ----
    const int cx = tid & 31;            // cell x within tile
    const int cyq = tid >> 5;           // 0..7
    float* outb = out + (size_t)b * C * N;
    float* denb = den + (size_t)b * N;

    for (int q = 0; q < 4; ++q) {
        const int cy = cyq + 8 * q;
        float d = 0.f, n0 = 0.f, n1 = 0.f, n2 = 0.f;
#pragma unroll
        for (int jy = 0; jy < 2; ++jy) {
            const int by = cy + jy;     // shifted: y0 = Y-1+jy
#pragma unroll
            for (int jx = 0; jx < 2; ++jx) {
                const int bx = cx + jx; // shifted: x0 = X-1+jx
                const int bin = by * BDIM + bx;
                const int cnt = min((int)binCnt[bin], K);
                for (int e = 0; e < cnt; ++e) {
                    const int i = ent[bin * K + e];
                    const float dx = recDx[i];
                    const float dy = recDy[i];
                    const unsigned uv01 = recV01[i];
                    const unsigned uv2 = recV2[i];
                    const float2 v01 = __half22float2(*(const __half2*)&uv01);
                    const float v2 = __half2float(((const __half2*)&uv2)->x);
                    // jx==1 -> x0==X -> wx = 1-dx ; jx==0 -> X==x0+1 -> wx = dx
                    const float wx = jx ? (1.f - dx) : dx;
                    const float wy = jy ? (1.f - dy) : dy;
                    const float w = wx * wy;
                    d += w;
                    n0 += v01.x * w;
                    n1 += v01.y * w;
                    n2 += v2 * w;
                }
            }
        }
        const float inv = 1.f / fmaxf(d, EPS);
        const int gi = (ty0 + cy) * W + tx0 + cx;
        denb[gi] = d;
        outb[gi]         = n0 * inv;
        outb[N + gi]     = n1 * inv;
        outb[2 * N + gi] = n2 * inv;
    }
}

// Apply fixup records exactly: un-normalize affected cells, add, re-normalize.
// One block per tile; records for the same cell are merged (first-index wins).
__global__ __launch_bounds__(64) void fix_tiles(
    float* __restrict__ out,          // [B,C,N] normalized
    float* __restrict__ den,          // [B,N]
    const int* __restrict__ tileCnt,
    const OutlierRec* __restrict__ recs,
    int slots)
{
    const int bid = blockIdx.x;
    int cnt = tileCnt[bid];
    if (cnt <= 0) return;
    cnt = min(cnt, slots);
    const int tid = threadIdx.x;
    if (tid >= cnt) return;

    OutlierRec rec = recs[(size_t)bid * slots + tid];
    float dw = rec.dw, d0 = rec.d0, d1 = rec.d1, d2 = rec.d2;
    bool first = true;
    for (int r2 = 0; r2 < cnt; ++r2) {
        if (r2 == tid) continue;
        OutlierRec o = recs[(size_t)bid * slots + r2];
        if (o.idx == rec.idx) {
            if (r2 < tid) { first = false; break; }
            dw += o.dw; d0 += o.d0; d1 += o.d1; d2 += o.d2;
        }
    }
    if (!first) return;

    const int b = rec.idx >> 20;          // idx / N
    const int cell = rec.idx & (N - 1);
    float* outb = out + (size_t)b * C * N + cell;
    float* dptr = den + ((size_t)b << 20) + cell;

    float d = *dptr;
    const float m = fmaxf(d, EPS);
    float n0 = outb[0] * m;               // recover numerators
    float n1 = outb[N] * m;
    float n2 = outb[2 * N] * m;
    d += dw; n0 += d0; n1 += d1; n2 += d2;
    const float inv = 1.f / fmaxf(d, EPS);
    *dptr = d;
    outb[0]     = n0 * inv;
    outb[N]     = n1 * inv;
    outb[2 * N] = n2 * inv;
}

extern "C" void kernel_launch(void* const* d_in, const int* in_sizes, int n_in,
                              void* d_out, int out_size, void* d_ws, size_t ws_size,
                              hipStream_t stream) {
    const float* im0 = (const float*)d_in[0];   // [B,C,H,W] fp32
    const float* grid = (const float*)d_in[1];  // [B,H,W,2] fp32
    float* out = (float*)d_out;                 // [B,C,H,W] fp32

    // ws layout: [0,16K): per-tile record counts | [16K, 16K+16MB): den |
    //            rest: per-tile fixup record slots
    int* tileCnt = (int*)d_ws;
    float* den = (float*)((char*)d_ws + 16384);
    const size_t rec_off = 16384 + (size_t)B * N * sizeof(float);
    OutlierRec* recs = (OutlierRec*)((char*)d_ws + rec_off);
    int slots = 0;
    if (ws_size > rec_off) {
        size_t avail = (ws_size - rec_off) / sizeof(OutlierRec);
        slots = (int)(avail / NTILES);
        if (slots > 32) slots = 32;
    }

    (void)hipMemsetAsync(tileCnt, 0, NTILES * sizeof(int), stream);

    splat_gather<<<NTILES, 256, 0, stream>>>(im0, grid, out, den,
                                             tileCnt, recs, slots);
    fix_tiles<<<NTILES, 64, 0, stream>>>(out, den, tileCnt, recs, slots);
}